// Round 1
// baseline (244.657 us; speedup 1.0000x reference)
//
#include <hip/hip_runtime.h>
#include <stdint.h>

// MomentumLIF: x[N,T,D] f32 -> spikes[N,T,D] f32 (0/1)
//   v_t = mom*v + x_t - lamb*u ; u_t = 0.5*u + v_t ; s = (u>=1); u *= (1-s)
//
// R9: single fused stream kernel.
//   - 4 adjacent chains (d, d+1, d+2, d+3) per thread -> every global access
//     is dwordx4 (16 B/lane, 1 KB/wave/instr), the measured BW sweet spot.
//   - 8-deep register ring of float4 x-tiles, fully unrolled; LLVM's waitcnt
//     pass handles the mixed load/store vmcnt pipeline.
//   - spikes written directly as nontemporal float4 (no ws round-trip, no
//     second dispatch, no graph dependency gap).
//   - arithmetic order identical to the absmax==0 R8 kernel (contract off).

#define N_ 64
#define T_ 64
#define D_ 8192
#define PF 8    // load pipeline depth (float4 tiles in flight per thread)
#define CPT 4   // chains per thread

typedef __attribute__((ext_vector_type(4))) float f32x4;

__global__ __launch_bounds__(256) void lif_fused(
    const float* __restrict__ x,
    const float* __restrict__ momp,
    const float* __restrict__ lambp,
    float* __restrict__ out)
{
    // Match numpy f32 semantics exactly: no FMA contraction anywhere.
#pragma clang fp contract(off)
    const float mom   = momp[0];
    const float lamb  = lambp[0];
    const float decay = 0.5f;   // 1 - 1/TAU, exact

    const int g  = blockIdx.x * blockDim.x + threadIdx.x;  // 0 .. N*D/4 - 1
    const int n  = g >> 11;                  // g / (D_/CPT)
    const int dq = g & 2047;                 // float4 index within a row
    const size_t base = (size_t)n * (size_t)(T_ * D_) + ((size_t)dq << 2);

    const f32x4* __restrict__ xv = reinterpret_cast<const f32x4*>(x + base);
    f32x4* __restrict__ ov       = reinterpret_cast<f32x4*>(out + base);
    const int RS = D_ / 4;                   // row stride in f32x4 units

    // Prologue: fill the 8-deep ring.
    f32x4 buf[PF];
#pragma unroll
    for (int i = 0; i < PF; ++i) buf[i] = xv[(size_t)i * RS];

    float u[CPT] = {0.f, 0.f, 0.f, 0.f};
    float v[CPT] = {0.f, 0.f, 0.f, 0.f};

    // Main loop: consume slot, refill with t+PF, step recurrence, store.
#pragma unroll
    for (int t = 0; t < T_ - PF; ++t) {
        const f32x4 xt = buf[t & (PF - 1)];
        buf[t & (PF - 1)] = xv[(size_t)(t + PF) * RS];

        f32x4 o;
#pragma unroll
        for (int c = 0; c < CPT; ++c) {
            const float t1 = mom * v[c];     // separately rounded, matches numpy
            const float t2 = lamb * u[c];
            v[c] = (t1 + xt[c]) - t2;
            u[c] = decay * u[c] + v[c];
            const bool sp = (u[c] >= 1.0f);
            o[c] = sp ? 1.0f : 0.0f;
            u[c] = sp ? 0.0f : u[c];         // u*(1-s) is exactly this select
        }
        __builtin_nontemporal_store(o, ov + (size_t)t * RS);
    }

    // Epilogue: drain the ring, no more loads.
#pragma unroll
    for (int t = T_ - PF; t < T_; ++t) {
        const f32x4 xt = buf[t & (PF - 1)];

        f32x4 o;
#pragma unroll
        for (int c = 0; c < CPT; ++c) {
            const float t1 = mom * v[c];
            const float t2 = lamb * u[c];
            v[c] = (t1 + xt[c]) - t2;
            u[c] = decay * u[c] + v[c];
            const bool sp = (u[c] >= 1.0f);
            o[c] = sp ? 1.0f : 0.0f;
            u[c] = sp ? 0.0f : u[c];
        }
        __builtin_nontemporal_store(o, ov + (size_t)t * RS);
    }
}

extern "C" void kernel_launch(void* const* d_in, const int* in_sizes, int n_in,
                              void* d_out, int out_size, void* d_ws, size_t ws_size,
                              hipStream_t stream) {
    const float* x    = (const float*)d_in[0];
    const float* momp = (const float*)d_in[1];
    const float* lamb = (const float*)d_in[2];
    float* out = (float*)d_out;

    dim3 block(256);
    dim3 grid((N_ * D_ / CPT) / 256);   // 512 blocks, one thread per 4 chains
    hipLaunchKernelGGL(lif_fused, grid, block, 0, stream, x, momp, lamb, out);
}